// Round 11
// baseline (542.403 us; speedup 1.0000x reference)
//
#include <hip/hip_runtime.h>
#include <math.h>

#define EPSV 1e-6f
#define NTOK 8192
#define NE   16384
#define DIM  256
#define QCAP (1u << 20)

using short8 = __attribute__((ext_vector_type(8))) short;
using f32x4v = __attribute__((ext_vector_type(4))) float;

__device__ __forceinline__ unsigned short f2bf(float v) {
    unsigned int u = __float_as_uint(v);
    u += 0x7fffu + ((u >> 16) & 1u);   // RNE
    return (unsigned short)(u >> 16);
}
__device__ __forceinline__ float bf2f(unsigned short h) {
    return __uint_as_float(((unsigned int)h) << 16);
}

__device__ __forceinline__ void gload_lds16(const void* g, void* s) {
    __builtin_amdgcn_global_load_lds(
        (const __attribute__((address_space(1))) void*)g,
        (__attribute__((address_space(3))) void*)s, 16, 0, 0);
}

// split 8 consecutive fp32 into bf16 hi/lo fragments
__device__ __forceinline__ void split8(const float4 a, const float4 b,
                                       short8& h, short8& l) {
    float f[8] = {a.x, a.y, a.z, a.w, b.x, b.y, b.z, b.w};
#pragma unroll
    for (int j = 0; j < 8; ++j) {
        unsigned short hh = f2bf(f[j]);
        h[j] = (short)hh;
        l[j] = (short)f2bf(f[j] - bf2f(hh));
    }
}

// ---------------------------------------------------------------- F0:
// blocks [0,128): z transpose + zh + per-token sz (fp64) + nzl2 (|zl|^2).
// blocks [128,384): emb = cb @ W.T (4-term bf16x2 MFMA) + eh + se partials
// + atomicMax bounds for |e|^2 and |el|^2 (scal[0], scal[1]).
__global__ __launch_bounds__(256, 2) void f0_pre(
    const float* __restrict__ zin, float* __restrict__ z_flat,
    unsigned short* __restrict__ zh, float* __restrict__ sz,
    float* __restrict__ nzl2, const float* __restrict__ cb,
    const float* __restrict__ Wm, float* __restrict__ emb,
    unsigned short* __restrict__ eh, float* __restrict__ se0,
    float* __restrict__ se1, unsigned int* __restrict__ scal) {
    __shared__ char smemC[65536];
    const int tid = threadIdx.x;

    if (blockIdx.x < 128) {            // ================= z path
        float (*tile)[65] = (float(*)[65])smemC;
        const int bid = blockIdx.x;
        const int yx0 = (bid & 15) * 64, b = bid >> 4;
        const int sub = tid >> 6, ln = tid & 63;
        double dacc[16];
        float lacc[16];
#pragma unroll
        for (int j = 0; j < 16; ++j) { dacc[j] = 0.0; lacc[j] = 0.0f; }

        for (int cc = 0; cc < 4; ++cc) {
            const int c0 = cc * 64;
            __syncthreads();
#pragma unroll
            for (int j = 0; j < 16; ++j) {
                int cl = j * 4 + sub;
                tile[cl][ln] = zin[((size_t)(b * 256 + c0 + cl) << 10) + yx0 + ln];
            }
            __syncthreads();
#pragma unroll
            for (int j = 0; j < 16; ++j) {
                int tl = j * 4 + sub;
                float v = tile[ln][tl];
                size_t o = (size_t)(b * 1024 + yx0 + tl) * 256 + c0 + ln;
                z_flat[o] = v;
                unsigned short h = f2bf(v);
                zh[o] = h;
                float zl = v - bf2f(h);
                lacc[j] = fmaf(zl, zl, lacc[j]);
                dacc[j] += (double)v * v;
            }
        }
#pragma unroll
        for (int j = 0; j < 16; ++j) {
            double s = dacc[j];
            float l2 = lacc[j];
#pragma unroll
            for (int m = 1; m < 64; m <<= 1) {
                s += __shfl_xor(s, m);
                l2 += __shfl_xor(l2, m);
            }
            if (ln == 0) {
                sz[b * 1024 + yx0 + j * 4 + sub] = (float)s;
                nzl2[b * 1024 + yx0 + j * 4 + sub] = l2;
            }
        }
        return;
    }

    // ================= emb GEMM path
    const int bid2 = blockIdx.x - 128;
    const int w = tid >> 6, lane = tid & 63;
    const int quad = lane >> 4, lr = lane & 15;
    const int wr = w & 1, wc = w >> 1;
    const int n0 = (bid2 & 127) * 128, c0 = (bid2 >> 7) * 128;

    f32x4v acc[4][4];
#pragma unroll
    for (int mt = 0; mt < 4; ++mt)
#pragma unroll
        for (int nt = 0; nt < 4; ++nt)
            acc[mt][nt] = (f32x4v){0.f, 0.f, 0.f, 0.f};

    for (int kc = 0; kc < 4; ++kc) {
        __syncthreads();
#pragma unroll
        for (int i = 0; i < 16; ++i) {
            int s = i * 4 + w;           // wave-uniform segment 0..63
            int u = s * 64 + lane;       // global unit 0..4095
            const void* g;
            if (s < 32) {                // cbS: [kg(16)][row(128)] fp32x4
                int kg = u >> 7, row = u & 127;
                g = cb + (size_t)(n0 + row) * 256 + kc * 64 + kg * 4;
            } else {                     // wS fp32: [kg(16)][row(128)]
                int u1 = u - 2048;
                int kg = u1 >> 7, row = u1 & 127;
                g = Wm + (size_t)(c0 + row) * 256 + kc * 64 + kg * 4;
            }
            gload_lds16(g, smemC + ((size_t)u << 4));
        }
        __syncthreads();
#pragma unroll
        for (int ks = 0; ks < 2; ++ks) {
            short8 Ah[4], Al[4], Bh[4], Bl[4];
#pragma unroll
            for (int mt = 0; mt < 4; ++mt) {
                int m = wr * 64 + mt * 16 + lr;
                int kg2 = ks * 8 + quad * 2;
                float4 f0 = *(const float4*)(smemC + (((size_t)kg2 * 128 + m) << 4));
                float4 f1 = *(const float4*)(smemC + ((((size_t)kg2 + 1) * 128 + m) << 4));
                split8(f0, f1, Ah[mt], Al[mt]);
            }
#pragma unroll
            for (int nt = 0; nt < 4; ++nt) {
                int n = wc * 64 + nt * 16 + lr;
                int kg2 = ks * 8 + quad * 2;
                float4 g0 = *(const float4*)(smemC + (((size_t)(2048 + kg2 * 128 + n)) << 4));
                float4 g1 = *(const float4*)(smemC + (((size_t)(2048 + (kg2 + 1) * 128 + n)) << 4));
                split8(g0, g1, Bh[nt], Bl[nt]);
            }
#pragma unroll
            for (int mt = 0; mt < 4; ++mt)
#pragma unroll
                for (int nt = 0; nt < 4; ++nt) {
                    f32x4v a = acc[mt][nt];
                    a = __builtin_amdgcn_mfma_f32_16x16x32_bf16(Ah[mt], Bh[nt], a, 0, 0, 0);
                    a = __builtin_amdgcn_mfma_f32_16x16x32_bf16(Ah[mt], Bl[nt], a, 0, 0, 0);
                    a = __builtin_amdgcn_mfma_f32_16x16x32_bf16(Al[mt], Bh[nt], a, 0, 0, 0);
                    a = __builtin_amdgcn_mfma_f32_16x16x32_bf16(Al[mt], Bl[nt], a, 0, 0, 0);
                    acc[mt][nt] = a;
                }
        }
    }
#pragma unroll
    for (int mt = 0; mt < 4; ++mt)
#pragma unroll
        for (int rr = 0; rr < 4; ++rr) {
            int row = n0 + wr * 64 + mt * 16 + quad * 4 + rr;
#pragma unroll
            for (int nt = 0; nt < 4; ++nt) {
                int col = c0 + wc * 64 + nt * 16 + lr;
                size_t o = (size_t)row * 256 + col;
                float v = acc[mt][nt][rr];
                emb[o] = v;
                eh[o] = f2bf(v);
            }
        }
    // ---- se & |el|^2 partials over this block's 128 cols
    __syncthreads();
    float* sblk = (float*)smemC;        // [2][128]
    float* eblk = sblk + 256;           // [2][128]
#pragma unroll
    for (int mt = 0; mt < 4; ++mt)
#pragma unroll
        for (int rr = 0; rr < 4; ++rr) {
            float s = 0.f, e2 = 0.f;
#pragma unroll
            for (int nt = 0; nt < 4; ++nt) {
                float v = acc[mt][nt][rr];
                s = fmaf(v, v, s);
                float el = v - bf2f(f2bf(v));
                e2 = fmaf(el, el, e2);
            }
#pragma unroll
            for (int st = 1; st < 16; st <<= 1) {
                s += __shfl_xor(s, st);
                e2 += __shfl_xor(e2, st);
            }
            if (lr == 0) {
                int idx = wc * 128 + wr * 64 + mt * 16 + quad * 4 + rr;
                sblk[idx] = s;
                eblk[idx] = e2;
            }
        }
    __syncthreads();
    if (tid < 128) {
        float* sep = ((bid2 >> 7) == 0) ? se0 : se1;
        float vse = sblk[tid] + sblk[128 + tid];
        float vel = eblk[tid] + eblk[128 + tid];
        sep[n0 + tid] = vse;
        // block-local max -> atomicMax (positive floats as uints)
#pragma unroll
        for (int st = 1; st < 64; st <<= 1) {
            vse = fmaxf(vse, __shfl_xor(vse, st));
            vel = fmaxf(vel, __shfl_xor(vel, st));
        }
        if ((tid & 63) == 0) {
            atomicMax(&scal[0], __float_as_uint(vse));
            atomicMax(&scal[1], __float_as_uint(vel));
        }
    }
}

// ---------------------------------------------------------------- K1 pass1:
// 1-term bf16 screen: d~ = se - 2*(zh.eh). Per-(row, 32-code chunk) min.
// cmin buffered in VGPRs (lane lr keeps chunk c4 via cndmask), flushed as
// 8 coalesced stores per 16 chunks — no per-chunk scattered stores/drains.
__global__ __launch_bounds__(256, 2) void k1_pass1(
    const unsigned short* __restrict__ zh, const unsigned short* __restrict__ eh,
    const float* __restrict__ se0, const float* __restrict__ se1,
    float* __restrict__ cmin) {
    __shared__ short8 smem[2][1024];   // 2 x 16 KB
    const int tid = threadIdx.x;
    const int w = tid >> 6, lane = tid & 63;
    const int quad = lane >> 4, lr = lane & 15;
    const int tokBase = blockIdx.x * 128;
    const int rowBase = tokBase + w * 32;
    const int slab = blockIdx.y;
    const int slabBase = slab * 2048;

    short8 Ah[2][8];                   // hi-only A: 64 VGPRs
#pragma unroll
    for (int mt = 0; mt < 2; ++mt)
#pragma unroll
        for (int ks = 0; ks < 8; ++ks) {
            size_t o = (size_t)(rowBase + mt * 16 + lr) * 256 + ks * 32 + quad * 8;
            Ah[mt][ks] = *(const short8*)(zh + o);
        }

    auto stage = [&](int buf, int ch) {
        const int colBase = slabBase + ch * 32;
#pragma unroll
        for (int i = 0; i < 4; ++i) {
            int u = i * 256 + tid;      // 0..1023
            int col = u >> 5, kgs = u & 31;
            int kg = kgs ^ col;         // XOR swizzle
            const unsigned short* g =
                eh + (size_t)(colBase + col) * 256 + kg * 8;
            gload_lds16(g, (char*)&smem[0][0] + buf * 16384 +
                               (((size_t)i * 256 + w * 64) << 4));
        }
    };

    stage(0, 0);
    __syncthreads();

    for (int cb = 0; cb < 4; ++cb) {
        float bmin8[8];
#pragma unroll
        for (int k = 0; k < 8; ++k) bmin8[k] = INFINITY;
#pragma unroll 1
        for (int c4 = 0; c4 < 16; ++c4) {
            const int ch = cb * 16 + c4;
            const int cur = ch & 1;
            if (ch + 1 < 64) stage(cur ^ 1, ch + 1);  // async prefetch

            const int colg0 = slabBase + ch * 32 + lr;
            const float sec0 = se0[colg0] + se1[colg0];
            const float sec1 = se0[colg0 + 16] + se1[colg0 + 16];

            f32x4v acc[2][2];
#pragma unroll
            for (int mt = 0; mt < 2; ++mt)
#pragma unroll
                for (int nt = 0; nt < 2; ++nt)
                    acc[mt][nt] = (f32x4v){0.f, 0.f, 0.f, 0.f};

#pragma unroll
            for (int ks = 0; ks < 8; ++ks) {
                short8 Bh[2];
#pragma unroll
                for (int nt = 0; nt < 2; ++nt) {
                    int col = nt * 16 + lr;
                    int kgs = (ks * 4 + quad) ^ col;
                    Bh[nt] = smem[cur][col * 32 + kgs];
                }
#pragma unroll
                for (int mt = 0; mt < 2; ++mt)
#pragma unroll
                    for (int nt = 0; nt < 2; ++nt)
                        acc[mt][nt] = __builtin_amdgcn_mfma_f32_16x16x32_bf16(
                            Ah[mt][ks], Bh[nt], acc[mt][nt], 0, 0, 0);
            }

            // chunk-min per row; all 16 lanes converge; lane lr keeps c4==lr
#pragma unroll
            for (int mt = 0; mt < 2; ++mt)
#pragma unroll
                for (int rr = 0; rr < 4; ++rr) {
                    float d0 = fmaf(-2.0f, acc[mt][0][rr], sec0);
                    float d1 = fmaf(-2.0f, acc[mt][1][rr], sec1);
                    float dm = fminf(d0, d1);
#pragma unroll
                    for (int st = 1; st < 16; st <<= 1)
                        dm = fminf(dm, __shfl_xor(dm, st));
                    const int k = mt * 4 + rr;
                    bmin8[k] = (lr == c4) ? dm : bmin8[k];
                }
            __syncthreads();
        }
        // coalesced flush: lane (quad, lr) holds (row-group quad, chunk lr)
#pragma unroll
        for (int k = 0; k < 8; ++k) {
            int row = rowBase + (k >> 2) * 16 + quad * 4 + (k & 3);
            cmin[(size_t)row * 512 + slab * 64 + cb * 16 + lr] = bmin8[k];
        }
    }
}

// ---------------------------------------------------------------- K2a:
// per-token: m0 over 512 chunk-mins; tight per-token margin; emit flagged
// (token,chunk) pairs to queue; init bmin.
__global__ __launch_bounds__(256) void k2a_emit(
    const float* __restrict__ cmin, const float* __restrict__ sz,
    const float* __restrict__ nzl2, const unsigned int* __restrict__ scal,
    unsigned int* __restrict__ qcnt, unsigned int* __restrict__ queue,
    unsigned long long* __restrict__ bmin) {
    const int w = threadIdx.x >> 6, lane = threadIdx.x & 63;
    const int t = blockIdx.x * 4 + w;
    if (lane == 0) bmin[t] = ~0ull;

    float cm[8];
#pragma unroll
    for (int r = 0; r < 8; ++r)
        cm[r] = cmin[(size_t)t * 512 + r * 64 + lane];
    float m0 = cm[0];
#pragma unroll
    for (int r = 1; r < 8; ++r) m0 = fminf(m0, cm[r]);
#pragma unroll
    for (int st = 1; st < 64; st <<= 1) m0 = fminf(m0, __shfl_xor(m0, st));

    // margin: |d~ - d_exact| <= nzl*|e|max + (|z|+nzl)*|el|max + slack.
    // scal partial maxes are per-128-col halves: bound full norms by 2x.
    const float EM = sqrtf(2.0f * __uint_as_float(scal[0]));
    const float ELM = sqrtf(2.0f * __uint_as_float(scal[1]));
    const float nzl = sqrtf(nzl2[t]);
    const float B = nzl * EM + (sqrtf(sz[t]) + nzl) * ELM + 1.5e-3f;
    const float thresh = m0 + 2.0f * B;

#pragma unroll
    for (int r = 0; r < 8; ++r) {
        if (cm[r] <= thresh) {
            unsigned int off = atomicAdd(qcnt, 1u);
            if (off < QCAP)
                queue[off] = (unsigned int)(t * 512 + r * 64 + lane);
        }
    }
}

// ---------------------------------------------------------------- K2b:
// load-balanced exact re-rank: one wave per queue entry; each of the 32
// rows is read as ONE fully-coalesced 1KB instruction; lexicographic
// (d, j) min folded into bmin[t] via sortable-u64 atomicMin.
__global__ __launch_bounds__(256) void k2b_rank(
    const float* __restrict__ z_flat, const float* __restrict__ emb,
    const float* __restrict__ se0, const float* __restrict__ se1,
    const unsigned int* __restrict__ qcnt, const unsigned int* __restrict__ queue,
    unsigned long long* __restrict__ bmin) {
    const int lane = threadIdx.x & 63;
    const int wid = (blockIdx.x * 256 + threadIdx.x) >> 6;
    const int nW = gridDim.x * 4;
    const unsigned int n = min(*qcnt, QCAP);

    for (unsigned int i = wid; i < n; i += nW) {
        const unsigned int e = queue[i];
        const int t = e >> 9, c = e & 511;
        const int j0 = (c >> 6) * 2048 + (c & 63) * 32;
        const float4 zv = *(const float4*)(z_flat + (size_t)t * 256 + lane * 4);
        float bd = INFINITY;
        int bj = 0;
#pragma unroll 1
        for (int rr = 0; rr < 32; ++rr) {
            const int j = j0 + rr;
            const float4 ev = *(const float4*)(emb + (size_t)j * 256 + lane * 4);
            float p = fmaf(zv.x, ev.x, fmaf(zv.y, ev.y,
                      fmaf(zv.z, ev.z, zv.w * ev.w)));
#pragma unroll
            for (int st = 1; st < 64; st <<= 1) p += __shfl_xor(p, st);
            float d = fmaf(-2.0f, p, se0[j] + se1[j]);
            if (d < bd) { bd = d; bj = j; }   // ascending j: first-min wins
        }
        if (lane == 0) {
            unsigned int u = __float_as_uint(bd);
            unsigned int s = (u & 0x80000000u) ? ~u : (u | 0x80000000u);
            unsigned long long key =
                ((unsigned long long)s << 32) | (unsigned int)bj;
            atomicMin(&bmin[t], key);
        }
    }
}

// ---------------------------------------------------------------- K3a:
// per-token: decode best from bmin; exact zes; rotation scalars; loss.
__global__ __launch_bounds__(256) void k3a_token(
    const float* __restrict__ z_flat, const float* __restrict__ emb,
    const unsigned long long* __restrict__ bmin, const float* __restrict__ sz,
    const float* __restrict__ se0, const float* __restrict__ se1,
    float* __restrict__ alpha, float* __restrict__ beta,
    int* __restrict__ idxf, float* __restrict__ out,
    float* __restrict__ lpart) {
    __shared__ float red[4];
    const int w = threadIdx.x >> 6, lane = threadIdx.x & 63;
    const int t = blockIdx.x * 4 + w;
    const int best = (int)(unsigned int)(bmin[t] & 0xFFFFFFFFull);

    const float4 zv = *(const float4*)(z_flat + (size_t)t * 256 + lane * 4);
    const float4 ev = *(const float4*)(emb + (size_t)best * 256 + lane * 4);
    float zes = zv.x * ev.x + zv.y * ev.y + zv.z * ev.z + zv.w * ev.w;
#pragma unroll
    for (int m = 1; m < 64; m <<= 1) zes += __shfl_xor(zes, m);

    if (lane == 0) {
        const float szs = sz[t];
        const float ses = se0[best] + se1[best];
        const float sqs = szs + ses - 2.0f * zes;
        float ns = sqrtf(szs), nt = sqrtf(ses);
        float inv_s = 1.0f / (ns + EPSV);
        float inv_t = 1.0f / (nt + EPSV);
        float s2 = szs * inv_s;                      // z . u
        float su = szs * inv_s * inv_s;
        float sq = ses * inv_t * inv_t;
        float uq = zes * inv_s * inv_t;
        float nw = sqrtf(su + sq + 2.0f * uq);
        float inv_w = 1.0f / (nw + EPSV);
        float s1 = (s2 + zes * inv_t) * inv_w;       // z . w_
        float scale = nt * inv_s;
        float a = scale * (1.0f - 2.0f * s1 * inv_w * inv_s);
        float bb = scale * inv_t * 2.0f * (s2 - s1 * inv_w);
        alpha[t] = a;
        beta[t] = bb;
        idxf[t] = best;
        out[2097153 + t] = (float)best;
        red[w] = sqs;
    }
    __syncthreads();
    if (threadIdx.x == 0)
        lpart[blockIdx.x] = red[0] + red[1] + red[2] + red[3];
}

// ---------------------------------------------------------------- K3b:
// Tiled z_q; block (0,0) reduces the loss.
__global__ __launch_bounds__(256) void k3b_zq(
    const float* __restrict__ z_flat, const float* __restrict__ emb,
    const float* __restrict__ alpha, const float* __restrict__ beta,
    const int* __restrict__ idxf, const float* __restrict__ lpart,
    float* __restrict__ out) {
    __shared__ float Q[64][65];
    __shared__ float Asm[64], Bsm[64];
    __shared__ int Ism[64];
    const int tid = threadIdx.x;
    const int t0 = blockIdx.x * 64;
    const int c0 = blockIdx.y * 64;

    if (blockIdx.x == 0 && blockIdx.y == 0) {
        __shared__ float red[4];
        float s = 0.0f;
        for (int i = tid; i < 2048; i += 256) s += lpart[i];
#pragma unroll
        for (int m = 1; m < 64; m <<= 1) s += __shfl_xor(s, m);
        if ((tid & 63) == 0) red[tid >> 6] = s;
        __syncthreads();
        if (tid == 0)
            out[2097152] = 1.25f * (red[0] + red[1] + red[2] + red[3]) *
                           (1.0f / 2097152.0f);
    }

    if (tid < 64) {
        Asm[tid] = alpha[t0 + tid];
        Bsm[tid] = beta[t0 + tid];
        Ism[tid] = idxf[t0 + tid];
    }
    __syncthreads();

    const int sub = tid >> 6, ln = tid & 63;
#pragma unroll
    for (int j = 0; j < 16; ++j) {
        int tl = j * 4 + sub;
        float e = emb[(size_t)Ism[tl] * 256 + c0 + ln];
        float zv = z_flat[(size_t)(t0 + tl) * 256 + c0 + ln];
        Q[tl][ln] = Asm[tl] * zv + Bsm[tl] * e;
    }
    __syncthreads();
    const int b = t0 >> 10, yx0 = t0 & 1023;
#pragma unroll
    for (int j = 0; j < 16; ++j) {
        int cl = j * 4 + sub;
        out[((size_t)(b * 256 + c0 + cl) << 10) + yx0 + ln] = Q[ln][cl];
    }
}

// ----------------------------------------------------------------
extern "C" void kernel_launch(void* const* d_in, const int* in_sizes, int n_in,
                              void* d_out, int out_size, void* d_ws,
                              size_t ws_size, hipStream_t stream) {
    (void)in_sizes; (void)n_in; (void)out_size; (void)ws_size;
    const float* zin = (const float*)d_in[0];
    const float* cb  = (const float*)d_in[1];
    const float* Wm  = (const float*)d_in[2];
    float* out = (float*)d_out;
    char* ws = (char*)d_ws;

    float*          z_flat = (float*)(ws + 0);                     //  8 MB
    unsigned short* zh     = (unsigned short*)(ws + 8388608);      //  4 MB
    float*          emb    = (float*)(ws + 12582912);              // 16 MB
    unsigned short* eh     = (unsigned short*)(ws + 29360128);     //  8 MB
    float*          sz     = (float*)(ws + 37748736);              // 32 KB
    float*          se0    = (float*)(ws + 37781504);              // 64 KB
    float*          se1    = (float*)(ws + 37847040);              // 64 KB
    float*          nzl2   = (float*)(ws + 37912576);              // 32 KB
    unsigned int*   scal   = (unsigned int*)(ws + 37945344);       // 256 B
    unsigned int*   qcnt   = (unsigned int*)(ws + 37945600);       // 256 B
    float*          alpha  = (float*)(ws + 37945856);              // 32 KB
    float*          beta   = (float*)(ws + 37978624);              // 32 KB
    int*            idxf   = (int*)(ws + 38011392);                // 32 KB
    float*          lpart  = (float*)(ws + 38044160);              //  8 KB
    unsigned long long* bmin = (unsigned long long*)(ws + 38052352); // 64 KB
    float*          cmin   = (float*)(ws + 38117888);              // 16 MB
    unsigned int*   queue  = (unsigned int*)(ws + 54895104);       //  4 MB

    hipMemsetAsync(ws + 37945344, 0, 512, stream);   // scal + qcnt
    f0_pre<<<384, 256, 0, stream>>>(zin, z_flat, zh, sz, nzl2, cb, Wm,
                                    emb, eh, se0, se1, scal);
    k1_pass1<<<dim3(64, 8), 256, 0, stream>>>(zh, eh, se0, se1, cmin);
    k2a_emit<<<2048, 256, 0, stream>>>(cmin, sz, nzl2, scal, qcnt, queue, bmin);
    k2b_rank<<<256, 256, 0, stream>>>(z_flat, emb, se0, se1, qcnt, queue, bmin);
    k3a_token<<<2048, 256, 0, stream>>>(z_flat, emb, bmin, sz, se0, se1,
                                        alpha, beta, idxf, out, lpart);
    k3b_zq<<<dim3(128, 4), 256, 0, stream>>>(z_flat, emb, alpha, beta, idxf,
                                             lpart, out);
}